// Round 16
// baseline (739.374 us; speedup 1.0000x reference)
//
#include <hip/hip_runtime.h>
#include <stdint.h>

#define B_    16
#define C_    512
#define HEADS 16
#define NTOK  49
#define ROWS  (16*56*56)   // 50176

typedef __attribute__((ext_vector_type(8))) __bf16 bf16x8;
typedef __attribute__((ext_vector_type(4))) float  f32x4;
typedef __attribute__((ext_vector_type(8))) unsigned short u16x8;
typedef __attribute__((ext_vector_type(4))) unsigned short u16x4;

#define AS1 __attribute__((address_space(1)))
#define AS3 __attribute__((address_space(3)))

__device__ __forceinline__ unsigned short f2bf(float f) {
  union { float f; uint32_t u; } x; x.f = f;
  uint32_t r = x.u + 0x7FFFu + ((x.u >> 16) & 1u);
  return (unsigned short)(r >> 16);
}
__device__ __forceinline__ float bf2f(unsigned short u) {
  union { uint32_t u; float f; } x; x.u = ((uint32_t)u) << 16;
  return x.f;
}

// token-order local row -> window-order local row (chunk starts at image boundary)
__device__ __forceinline__ int winmap(int grow) {
  const int b = grow / 3136;
  const int pos = grow - b * 3136;
  const int y = pos / 56, x = pos - y * 56;
  const int win = (y / 7) * 8 + (x / 7);
  const int r = (y % 7) * 7 + (x % 7);
  return b * 3136 + win * 49 + r;
}

// ---------------- GEMM (R10-verified best): C = A(MxK) * Bt(NxK)^T + epilogue
// EPI 0: +bias -> bf16.  EPI 1: +bias, tanh-GELU -> bf16.
// EPI 2: +bias +res -> f32.  EPI 3: +res -> f32 (accumulation chunks).
// 128x128 tile, BK=32, 4 waves (2Mx2N), 64x64/wave; zero-conflict swizzle
// (stage g=(u&3)^((row>>1)&3), read kq^((fr>>1)&3)); T1 XCD remap;
// counted vmcnt(4); T5 setprio.
template<int EPI>
__global__ __launch_bounds__(256, 4)
void gemm_bt(const unsigned short* __restrict__ A,
             const unsigned short* __restrict__ Bt,
             const float* __restrict__ bias,
             const float* __restrict__ res,
             void* __restrict__ outp,
             int N, int K, int ldb, int nbn)
{
  __shared__ __align__(16) unsigned short As[2][128*32];
  __shared__ __align__(16) unsigned short Bs[2][128*32];

  const int nwg = gridDim.x;
  const int q8 = nwg >> 3, r8 = nwg & 7;
  const int xcd = blockIdx.x & 7, ixc = blockIdx.x >> 3;
  const int l = (xcd < r8 ? xcd * (q8 + 1) : r8 * (q8 + 1) + (xcd - r8) * q8) + ixc;
  const int bm = l / nbn, bn = l % nbn;

  const int tid  = threadIdx.x;
  const int wave = tid >> 6;
  const int lane = tid & 63;
  const int wr = wave >> 1, wc = wave & 1;

  const unsigned short* aSrc[2];
  const unsigned short* bSrc[2];
  #pragma unroll
  for (int i = 0; i < 2; ++i) {
    const int u = tid + i * 256;
    const int srow = u >> 2;
    const int sg   = (u & 3) ^ ((srow >> 1) & 3);
    aSrc[i] = A  + (size_t)(bm * 128 + srow) * K + sg * 8;
    bSrc[i] = Bt + (size_t)(bn * 128 + srow) * ldb + sg * 8;
  }

  f32x4 acc[4][4] = {};
  const int fr = lane & 15;
  const int kq = lane >> 4;
  const int xrd = kq ^ ((fr >> 1) & 3);

  auto STAGE = [&](int buf, int t) {
    const int k0 = t << 5;
    #pragma unroll
    for (int i = 0; i < 2; ++i)
      __builtin_amdgcn_global_load_lds(
        (const AS1 void*)(aSrc[i] + k0),
        (AS3 void*)(&As[buf][(i * 256 + wave * 64) * 8]), 16, 0, 0);
    #pragma unroll
    for (int i = 0; i < 2; ++i)
      __builtin_amdgcn_global_load_lds(
        (const AS1 void*)(bSrc[i] + k0),
        (AS3 void*)(&Bs[buf][(i * 256 + wave * 64) * 8]), 16, 0, 0);
  };

  const int nt = K >> 5;
  STAGE(0, 0);
  for (int t = 0; t < nt; ++t) {
    const int c = t & 1;
    if (t + 1 < nt) {
      STAGE(c ^ 1, t + 1);
      asm volatile("s_waitcnt vmcnt(4)" ::: "memory");
    } else {
      asm volatile("s_waitcnt vmcnt(0)" ::: "memory");
    }
    __builtin_amdgcn_s_barrier();
    asm volatile("" ::: "memory");

    bf16x8 a[4], b[4];
    #pragma unroll
    for (int m = 0; m < 4; ++m)
      a[m] = *(const bf16x8*)&As[c][(wr * 64 + m * 16 + fr) * 32 + xrd * 8];
    #pragma unroll
    for (int n = 0; n < 4; ++n)
      b[n] = *(const bf16x8*)&Bs[c][(wc * 64 + n * 16 + fr) * 32 + xrd * 8];

    __builtin_amdgcn_s_setprio(1);
    #pragma unroll
    for (int m = 0; m < 4; ++m)
      #pragma unroll
      for (int n = 0; n < 4; ++n)
        acc[m][n] = __builtin_amdgcn_mfma_f32_16x16x32_bf16(a[m], b[n], acc[m][n], 0, 0, 0);
    __builtin_amdgcn_s_setprio(0);

    asm volatile("s_waitcnt lgkmcnt(0)" ::: "memory");
    __builtin_amdgcn_s_barrier();
    asm volatile("" ::: "memory");
  }

  const int rq = lane >> 4;
  #pragma unroll
  for (int m = 0; m < 4; ++m) {
    #pragma unroll
    for (int n = 0; n < 4; ++n) {
      const int gcol = bn * 128 + wc * 64 + n * 16 + fr;
      const float bv = (EPI == 3) ? 0.f : bias[gcol];
      #pragma unroll
      for (int r = 0; r < 4; ++r) {
        const int grow = bm * 128 + wr * 64 + m * 16 + rq * 4 + r;
        const size_t off = (size_t)grow * N + gcol;
        float v = acc[m][n][r] + bv;
        if (EPI == 0) {
          ((unsigned short*)outp)[off] = f2bf(v);
        } else if (EPI == 1) {
          const float u2 = 1.5957691216f * v * (1.0f + 0.044715f * v * v);
          v = v / (1.0f + __expf(-u2));
          ((unsigned short*)outp)[off] = f2bf(v);
        } else {
          ((float*)outp)[off] = v + res[off];
        }
      }
    }
  }
}

// ---------------- proj + LayerNorm2 fused: 128x512 tile (full row in-block).
// A = attnOut (DISJOINT buffer, window order, lda=512) gathered via winmap;
// writes outF (f32 x1) and outLn (bf16 LN2) - three disjoint buffers, no race.
// 8 waves (2M x 4N), per-wave 64x128, BK=32, acc[4][8].
__global__ __launch_bounds__(512, 2)
void proj_ln(const unsigned short* __restrict__ Aw,   // chunk attnOut (window order)
             const unsigned short* __restrict__ Bt,   // wpB (512x512)
             const float* __restrict__ bias,          // projb
             const float* __restrict__ xres,          // x + chunk offset
             const float* __restrict__ nw, const float* __restrict__ nb,
             float* __restrict__ outF,                // out + chunk offset
             unsigned short* __restrict__ outLn)      // bufX + chunk offset
{
  __shared__ __align__(16) unsigned short As[2][128*32];   // 16 KB
  __shared__ __align__(16) unsigned short Bs[2][512*32];   // 64 KB
  __shared__ float red[128][4][2];                         // 4 KB

  const int bm = blockIdx.x;
  const int tid  = threadIdx.x;
  const int wave = tid >> 6;
  const int lane = tid & 63;
  const int wr = wave >> 2, wc = wave & 3;   // 2 (M) x 4 (N)

  const int fr = lane & 15;
  const int kq = lane >> 4;
  const int xrd = kq ^ ((fr >> 1) & 3);

  // A: 1 load/thread (512 slots = 128 rows x 4 kgroups); token row -> winmap.
  const int arow = tid >> 2;
  const int ag   = (tid & 3) ^ ((arow >> 1) & 3);
  const int ga   = winmap(bm * 128 + arow);
  const unsigned short* aSrc = Aw + (size_t)ga * 512 + ag * 8;
  // B: 4 loads/thread (2048 slots = 512 rows x 4 kgroups). ldb = 512.
  const unsigned short* bSrc[4];
  #pragma unroll
  for (int i = 0; i < 4; ++i) {
    const int u = i * 512 + tid;
    const int row = u >> 2;
    const int g = (u & 3) ^ ((row >> 1) & 3);
    bSrc[i] = Bt + (size_t)row * 512 + g * 8;
  }

  f32x4 acc[4][8] = {};

  auto STAGE = [&](int buf, int t) {         // 5 loads/thread
    const int k0 = t << 5;
    __builtin_amdgcn_global_load_lds(
      (const AS1 void*)(aSrc + k0),
      (AS3 void*)(&As[buf][(wave * 64) * 8]), 16, 0, 0);
    #pragma unroll
    for (int i = 0; i < 4; ++i)
      __builtin_amdgcn_global_load_lds(
        (const AS1 void*)(bSrc[i] + k0),
        (AS3 void*)(&Bs[buf][(i * 512 + wave * 64) * 8]), 16, 0, 0);
  };

  const int nt = 16;                         // K = 512
  STAGE(0, 0);
  for (int t = 0; t < nt; ++t) {
    const int c = t & 1;
    if (t + 1 < nt) {
      STAGE(c ^ 1, t + 1);
      asm volatile("s_waitcnt vmcnt(5)" ::: "memory");
    } else {
      asm volatile("s_waitcnt vmcnt(0)" ::: "memory");
    }
    __builtin_amdgcn_s_barrier();
    asm volatile("" ::: "memory");

    bf16x8 a[4], b[8];
    #pragma unroll
    for (int m = 0; m < 4; ++m)
      a[m] = *(const bf16x8*)&As[c][(wr * 64 + m * 16 + fr) * 32 + xrd * 8];
    #pragma unroll
    for (int n = 0; n < 8; ++n)
      b[n] = *(const bf16x8*)&Bs[c][(wc * 128 + n * 16 + fr) * 32 + xrd * 8];

    __builtin_amdgcn_s_setprio(1);
    #pragma unroll
    for (int m = 0; m < 4; ++m)
      #pragma unroll
      for (int n = 0; n < 8; ++n)
        acc[m][n] = __builtin_amdgcn_mfma_f32_16x16x32_bf16(a[m], b[n], acc[m][n], 0, 0, 0);
    __builtin_amdgcn_s_setprio(0);

    asm volatile("s_waitcnt lgkmcnt(0)" ::: "memory");
    __builtin_amdgcn_s_barrier();
    asm volatile("" ::: "memory");
  }

  // ---------- fused epilogue: bias + residual + LN2 ----------
  const int rq = lane >> 4;
  float nwv[8], nbv[8], bv[8];
  #pragma unroll
  for (int n = 0; n < 8; ++n) {
    const int gcol = wc * 128 + n * 16 + fr;
    nwv[n] = nw[gcol]; nbv[n] = nb[gcol]; bv[n] = bias[gcol];
  }

  float s1[4][4], s2[4][4];
  #pragma unroll
  for (int m = 0; m < 4; ++m) {
    #pragma unroll
    for (int r = 0; r < 4; ++r) {
      const int growl = bm * 128 + wr * 64 + m * 16 + rq * 4 + r;
      float s = 0.f, ss = 0.f;
      #pragma unroll
      for (int n = 0; n < 8; ++n) {
        const int gcol = wc * 128 + n * 16 + fr;
        float v = acc[m][n][r] + bv[n] + xres[(size_t)growl * 512 + gcol];
        acc[m][n][r] = v;
        s += v; ss += v * v;
      }
      #pragma unroll
      for (int off = 1; off < 16; off <<= 1) {
        s  += __shfl_xor(s,  off);
        ss += __shfl_xor(ss, off);
      }
      s1[m][r] = s; s2[m][r] = ss;
    }
  }
  if (fr == 0) {
    #pragma unroll
    for (int m = 0; m < 4; ++m)
      #pragma unroll
      for (int r = 0; r < 4; ++r) {
        const int rl = wr * 64 + m * 16 + rq * 4 + r;
        red[rl][wc][0] = s1[m][r];
        red[rl][wc][1] = s2[m][r];
      }
  }
  __syncthreads();

  #pragma unroll
  for (int m = 0; m < 4; ++m) {
    #pragma unroll
    for (int r = 0; r < 4; ++r) {
      const int rl = wr * 64 + m * 16 + rq * 4 + r;
      const float S  = red[rl][0][0] + red[rl][1][0] + red[rl][2][0] + red[rl][3][0];
      const float SS = red[rl][0][1] + red[rl][1][1] + red[rl][2][1] + red[rl][3][1];
      const float mean = S * (1.0f / 512.0f);
      const float rstd = rsqrtf(SS * (1.0f / 512.0f) - mean * mean + 1e-5f);
      const size_t rowoff = (size_t)(bm * 128 + rl) * 512;
      #pragma unroll
      for (int n = 0; n < 8; ++n) {
        const int gcol = wc * 128 + n * 16 + fr;
        const float v = acc[m][n][r];
        outF[rowoff + gcol] = v;                                   // x1 (f32)
        outLn[rowoff + gcol] = f2bf((v - mean) * rstd * nwv[n] + nbv[n]);
      }
    }
  }
}

// ---------------- LayerNorm (f32 in) -> bf16 out. 1 wave per row of 512.
__global__ __launch_bounds__(256)
void ln_bf16(const float* __restrict__ x, const float* __restrict__ w,
             const float* __restrict__ b, unsigned short* __restrict__ out)
{
  const int row  = blockIdx.x * 4 + (threadIdx.x >> 6);
  const int lane = threadIdx.x & 63;
  const float4* xr = (const float4*)(x + (size_t)row * C_);
  const float4 u = xr[lane * 2];
  const float4 v = xr[lane * 2 + 1];
  const float vals[8] = {u.x,u.y,u.z,u.w,v.x,v.y,v.z,v.w};
  float s = 0.f, s2 = 0.f;
  #pragma unroll
  for (int j = 0; j < 8; ++j) { s += vals[j]; s2 += vals[j]*vals[j]; }
  #pragma unroll
  for (int off = 1; off < 64; off <<= 1) {
    s  += __shfl_xor(s,  off);
    s2 += __shfl_xor(s2, off);
  }
  const float mean = s * (1.0f/512.0f);
  const float rstd = rsqrtf(s2 * (1.0f/512.0f) - mean*mean + 1e-5f);
  u16x8 o;
  #pragma unroll
  for (int j = 0; j < 8; ++j) {
    const int col = lane * 8 + j;
    o[j] = f2bf((vals[j] - mean) * rstd * w[col] + b[col]);
  }
  *(u16x8*)&out[(size_t)row * C_ + lane * 8] = o;
}

// ---------------- Window attention: block = (window, 4-head quarter).
// 256 threads = 4 waves; wave = one head; wave-private LDS, no barriers.
// Online softmax with fixed m=0 (bounded logits). Output DENSE in WINDOW
// order into a DISJOINT attnOut buffer (full-line stores, no RMW; no
// aliasing with bufX or qkv).
__global__ __launch_bounds__(256)
void attn_win3(const unsigned short* __restrict__ qkv,
               const unsigned short* __restrict__ biasBf,
               unsigned short* __restrict__ woutb)    // chunk attnOut, window order
{
  __shared__ float Ksh[4][NTOK*32];
  __shared__ float Vsh[4][NTOK*32];
  __shared__ unsigned short Bsh[4][NTOK*NTOK];
  const int bi = blockIdx.x;
  const int qtr = bi & 3, winl = bi >> 2;      // local window within chunk
  const int bbl = winl >> 6, wy = (winl >> 3) & 7, wx = winl & 7;
  const int wave = threadIdx.x >> 6, lane = threadIdx.x & 63;
  const int head = qtr * 4 + wave;

  for (int i = lane; i < NTOK*NTOK; i += 64)
    Bsh[wave][i] = biasBf[head * (NTOK*NTOK) + i];

  float q[32];
  if (lane < NTOK) {
    const int r = lane / 7, c = lane % 7;
    const size_t gl = (size_t)bbl * 3136 + (size_t)((wy*7 + r) * 56 + (wx*7 + c));
    const unsigned short* qp = qkv + gl * 1536 + head * 32;
    #pragma unroll
    for (int d = 0; d < 32; d += 4) {
      const u16x4 qv = *(const u16x4*)&qp[d];
      const u16x4 kv = *(const u16x4*)&qp[512 + d];
      const u16x4 vv = *(const u16x4*)&qp[1024 + d];
      #pragma unroll
      for (int e = 0; e < 4; ++e) {
        q[d+e] = bf2f(qv[e]);
        Ksh[wave][lane*32 + d + e] = bf2f(kv[e]);
        Vsh[wave][lane*32 + d + e] = bf2f(vv[e]);
      }
    }
  }
  if (lane < NTOK) {
    float lsum = 0.f;
    float o[32];
    #pragma unroll
    for (int d = 0; d < 32; ++d) o[d] = 0.f;
    for (int j = 0; j < NTOK; ++j) {
      float dot = 0.f;
      #pragma unroll
      for (int d = 0; d < 32; ++d) dot += q[d] * Ksh[wave][j*32 + d];
      const float val = dot * 0.17677669529663687f
                      + bf2f(Bsh[wave][lane*NTOK + j]);
      const float e = __expf(val);
      lsum += e;
      #pragma unroll
      for (int d = 0; d < 32; ++d) o[d] += e * Vsh[wave][j*32 + d];
    }
    const float inv = 1.0f / lsum;
    unsigned short* op = woutb + ((size_t)winl * 49 + lane) * 512 + head * 32;
    #pragma unroll
    for (int d = 0; d < 32; d += 4) {
      u16x4 ov;
      #pragma unroll
      for (int e = 0; e < 4; ++e) ov[e] = f2bf(o[d+e] * inv);
      *(u16x4*)&op[d] = ov;
    }
  }
}

// ---------------- small prep kernels
__global__ void build_bias(const float* __restrict__ table, const int* __restrict__ idx,
                           unsigned short* __restrict__ biasBf)
{
  const int i = blockIdx.x * 256 + threadIdx.x;
  if (i >= HEADS * NTOK * NTOK) return;
  const int h  = i / (NTOK*NTOK);
  const int ij = i - h * (NTOK*NTOK);
  biasBf[i] = f2bf(table[idx[ij] * HEADS + h]);
}

__global__ void conv_bf16(const float* __restrict__ in, unsigned short* __restrict__ out, int n4)
{
  const int i = blockIdx.x * 256 + threadIdx.x;
  if (i >= n4) return;
  const float4 v = ((const float4*)in)[i];
  u16x4 o; o[0]=f2bf(v.x); o[1]=f2bf(v.y); o[2]=f2bf(v.z); o[3]=f2bf(v.w);
  ((u16x4*)out)[i] = o;
}

extern "C" void kernel_launch(void* const* d_in, const int* in_sizes, int n_in,
                              void* d_out, int out_size, void* d_ws, size_t ws_size,
                              hipStream_t stream)
{
  const float* x     = (const float*)d_in[0];
  const float* n1w   = (const float*)d_in[1];
  const float* n1b   = (const float*)d_in[2];
  const float* qkvw  = (const float*)d_in[3];
  const float* qkvb  = (const float*)d_in[4];
  const float* projw = (const float*)d_in[5];
  const float* projb = (const float*)d_in[6];
  const float* rbt   = (const float*)d_in[7];
  const float* n2w   = (const float*)d_in[8];
  const float* n2b   = (const float*)d_in[9];
  const float* fc1w  = (const float*)d_in[10];
  const float* fc1b  = (const float*)d_in[11];
  const float* fc2w  = (const float*)d_in[12];
  const float* fc2b  = (const float*)d_in[13];
  const int*   rpi   = (const int*)d_in[14];
  float* out = (float*)d_out;

  // ---- adaptive workspace: fixed region + bufX + reusable R ----
  char* p = (char*)d_ws;
  auto alloc = [&](size_t bytes) -> char* {
    char* q = p; p += (bytes + 255) & ~(size_t)255; return q;
  };
  unsigned short* wqB  = (unsigned short*)alloc((size_t)1536 * 512 * 2);
  unsigned short* wpB  = (unsigned short*)alloc((size_t)512  * 512 * 2);
  unsigned short* w1B  = (unsigned short*)alloc((size_t)2048 * 512 * 2);
  unsigned short* w2B  = (unsigned short*)alloc((size_t)512  * 2048 * 2);
  unsigned short* biasBf = (unsigned short*)alloc((size_t)HEADS * NTOK * NTOK * 2);
  unsigned short* bufX = (unsigned short*)alloc((size_t)ROWS * 512 * 2);
  const size_t used = (size_t)(p - (char*)d_ws);
  const size_t Rbytes = (ws_size > used) ? ws_size - used : 0;
  unsigned short* R = (unsigned short*)p;

  // Chunk region holds qkv (ic*3136*1536) + attnOut (ic*3136*512) shorts.
  int ic = 0;
  for (int c = 16; c >= 2; c >>= 1)
    if ((size_t)c * 3136 * 2048 * 2 <= Rbytes) { ic = c; break; }
  // mlp hidden chunk (R reused for mlp1 after the attention stage)
  int hc = 0;
  for (int c = 2048; c >= 128; c >>= 1)
    if ((size_t)ROWS * c * 2 <= Rbytes) { hc = c; break; }
  if (ic == 0 || hc == 0) return;

  conv_bf16<<<(1536*512/4 + 255)/256, 256, 0, stream>>>(qkvw, wqB, 1536*512/4);
  conv_bf16<<<(512*512/4  + 255)/256, 256, 0, stream>>>(projw, wpB, 512*512/4);
  conv_bf16<<<(2048*512/4 + 255)/256, 256, 0, stream>>>(fc1w, w1B, 2048*512/4);
  conv_bf16<<<(512*2048/4 + 255)/256, 256, 0, stream>>>(fc2w, w2B, 512*2048/4);
  build_bias<<<(HEADS*NTOK*NTOK + 255)/256, 256, 0, stream>>>(rbt, rpi, biasBf);

  // LN1 -> bf16
  ln_bf16<<<ROWS/4, 256, 0, stream>>>(x, n1w, n1b, bufX);

  // Per chunk: QKV -> attn (window-order dense into DISJOINT attnOut) ->
  // proj(+LN2): reads attnOut, writes out (f32) + bufX (bf16). No aliasing.
  unsigned short* attnOut = R + (size_t)ic * 3136 * 1536;
  for (int i0 = 0; i0 < B_; i0 += ic) {
    const size_t roff = (size_t)i0 * 3136;
    const int nbm = ic * 3136 / 128, nbn = 12;
    gemm_bt<0><<<nbm * nbn, 256, 0, stream>>>(
        bufX + roff * 512, wqB, qkvb, nullptr, R, 1536, 512, 512, nbn);
    attn_win3<<<ic*64*4, 256, 0, stream>>>(R, biasBf, attnOut);
    proj_ln<<<nbm, 512, 0, stream>>>(
        attnOut, wpB, projb, x + roff * 512, n2w, n2b,
        out + roff * 512, bufX + roff * 512);
  }

  // MLP (R now free -> mlp1). FC2 accumulates into out (bias in chunk 0).
  for (int h0 = 0; h0 < 2048; h0 += hc) {
    gemm_bt<1><<<(ROWS/128) * (hc/128), 256, 0, stream>>>(
        bufX, w1B + (size_t)h0*512, fc1b + h0, nullptr, R, hc, 512, 512, hc/128);
    if (h0 == 0)
      gemm_bt<2><<<(ROWS/128) * 4, 256, 0, stream>>>(
          R, w2B + h0, fc2b, out, out, 512, hc, 2048, 4);
    else
      gemm_bt<3><<<(ROWS/128) * 4, 256, 0, stream>>>(
          R, w2B + h0, nullptr, out, out, 512, hc, 2048, 4);
  }
}

// Round 17
// 716.840 us; speedup vs baseline: 1.0314x; 1.0314x over previous
//
#include <hip/hip_runtime.h>
#include <stdint.h>

#define B_    16
#define C_    512
#define HEADS 16
#define NTOK  49
#define ROWS  (16*56*56)   // 50176

typedef __attribute__((ext_vector_type(8))) __bf16 bf16x8;
typedef __attribute__((ext_vector_type(4))) float  f32x4;
typedef __attribute__((ext_vector_type(8))) unsigned short u16x8;
typedef __attribute__((ext_vector_type(4))) unsigned short u16x4;

#define AS1 __attribute__((address_space(1)))
#define AS3 __attribute__((address_space(3)))

__device__ __forceinline__ unsigned short f2bf(float f) {
  union { float f; uint32_t u; } x; x.f = f;
  uint32_t r = x.u + 0x7FFFu + ((x.u >> 16) & 1u);
  return (unsigned short)(r >> 16);
}
__device__ __forceinline__ float bf2f(unsigned short u) {
  union { uint32_t u; float f; } x; x.u = ((uint32_t)u) << 16;
  return x.f;
}

// token-order row -> window-order row (attn output layout); used by proj's A-gather
__device__ __forceinline__ int winmap(int grow) {
  const int b = grow / 3136;
  const int pos = grow - b * 3136;
  const int y = pos / 56, x = pos - y * 56;
  const int win = (y / 7) * 8 + (x / 7);
  const int r = (y % 7) * 7 + (x % 7);
  return b * 3136 + win * 49 + r;
}

// ---------------- GEMM (R10 configuration - session-verified best at 719us):
// C = A(MxK,bf16) * Bt(NxK,bf16,row-stride ldb)^T + epilogue
// EPI 0: +bias -> bf16.  EPI 1: +bias, tanh-GELU -> bf16.
// EPI 2: +bias +res -> f32.  EPI 3: +res -> f32 (accumulation chunks).
// GATHER: remap A rows token-order -> window-order (reads attn output).
// 128x128 tile, BK=32, 4 waves (2Mx2N), per-wave 64x64 (16 MFMA : 8 ds_read);
// launch_bounds(256,4) -> VGPR 64, 16 waves/CU (4 blocks) for TLP.
// Zero-conflict swizzle (stage g=(u&3)^((row>>1)&3), read kq^((fr>>1)&3);
// SQ_LDS_BANK_CONFLICT==0 measured R9/R10/R14/R16). T1 XCD remap, counted
// vmcnt(4), T5 setprio, 2-barrier RAW/WAR schedule.
// NOTE (R14-R16 post-mortem): proj+LN2 fusion and attn-in-place variants
// both regressed (~+20us); this separate-pass pipeline is the optimum found.
template<int EPI, int GATHER>
__global__ __launch_bounds__(256, 4)
void gemm_bt(const unsigned short* __restrict__ A,
             const unsigned short* __restrict__ Bt,
             const float* __restrict__ bias,
             const float* __restrict__ res,
             void* __restrict__ outp,
             int N, int K, int ldb, int nbn)
{
  __shared__ __align__(16) unsigned short As[2][128*32];   // 16 KB
  __shared__ __align__(16) unsigned short Bs[2][128*32];   // 16 KB

  // T1: bijective XCD-chunked remap (m204).
  const int nwg = gridDim.x;
  const int q8 = nwg >> 3, r8 = nwg & 7;
  const int xcd = blockIdx.x & 7, ixc = blockIdx.x >> 3;
  const int l = (xcd < r8 ? xcd * (q8 + 1) : r8 * (q8 + 1) + (xcd - r8) * q8) + ixc;
  const int bm = l / nbn, bn = l % nbn;

  const int tid  = threadIdx.x;
  const int wave = tid >> 6;
  const int lane = tid & 63;
  const int wr = wave >> 1, wc = wave & 1;   // 2 (M) x 2 (N), per-wave 64x64

  // Staging: 512 slots (128 rows x 4 kgroups x 16B) per matrix; 2 slots/thread.
  // Source kgroup = (u&3) ^ ((row>>1)&3)  (inverse of the read swizzle).
  const unsigned short* aSrc[2];
  const unsigned short* bSrc[2];
  #pragma unroll
  for (int i = 0; i < 2; ++i) {
    const int u = tid + i * 256;
    const int srow = u >> 2;
    const int sg   = (u & 3) ^ ((srow >> 1) & 3);
    int ga = bm * 128 + srow;
    if (GATHER) ga = winmap(ga);
    aSrc[i] = A  + (size_t)ga * K + sg * 8;
    bSrc[i] = Bt + (size_t)(bn * 128 + srow) * ldb + sg * 8;
  }

  f32x4 acc[4][4] = {};
  const int fr = lane & 15;                  // fragment row (A row / B col)
  const int kq = lane >> 4;                  // k-quarter (8 bf16) within 32
  const int xrd = kq ^ ((fr >> 1) & 3);      // read-side swizzle

  auto STAGE = [&](int buf, int t) {         // 4 gload_lds per thread
    const int k0 = t << 5;
    #pragma unroll
    for (int i = 0; i < 2; ++i)
      __builtin_amdgcn_global_load_lds(
        (const AS1 void*)(aSrc[i] + k0),
        (AS3 void*)(&As[buf][(i * 256 + wave * 64) * 8]), 16, 0, 0);
    #pragma unroll
    for (int i = 0; i < 2; ++i)
      __builtin_amdgcn_global_load_lds(
        (const AS1 void*)(bSrc[i] + k0),
        (AS3 void*)(&Bs[buf][(i * 256 + wave * 64) * 8]), 16, 0, 0);
  };

  const int nt = K >> 5;                     // K in {512,2048} -> nt in {16,64}
  STAGE(0, 0);
  for (int t = 0; t < nt; ++t) {
    const int c = t & 1;
    if (t + 1 < nt) {
      STAGE(c ^ 1, t + 1);                   // issue next tile BEFORE waiting
      asm volatile("s_waitcnt vmcnt(4)" ::: "memory");   // own tile-t loads done
    } else {
      asm volatile("s_waitcnt vmcnt(0)" ::: "memory");
    }
    __builtin_amdgcn_s_barrier();            // RAW: all waves' tile-t landed
    asm volatile("" ::: "memory");

    bf16x8 a[4], b[4];
    #pragma unroll
    for (int m = 0; m < 4; ++m)
      a[m] = *(const bf16x8*)&As[c][(wr * 64 + m * 16 + fr) * 32 + xrd * 8];
    #pragma unroll
    for (int n = 0; n < 4; ++n)
      b[n] = *(const bf16x8*)&Bs[c][(wc * 64 + n * 16 + fr) * 32 + xrd * 8];

    __builtin_amdgcn_s_setprio(1);
    #pragma unroll
    for (int m = 0; m < 4; ++m)
      #pragma unroll
      for (int n = 0; n < 4; ++n)
        acc[m][n] = __builtin_amdgcn_mfma_f32_16x16x32_bf16(a[m], b[n], acc[m][n], 0, 0, 0);
    __builtin_amdgcn_s_setprio(0);

    asm volatile("s_waitcnt lgkmcnt(0)" ::: "memory");   // WAR before restage
    __builtin_amdgcn_s_barrier();
    asm volatile("" ::: "memory");
  }

  const int rq = lane >> 4;                  // C/D: row=(lane>>4)*4+r, col=lane&15
  #pragma unroll
  for (int m = 0; m < 4; ++m) {
    #pragma unroll
    for (int n = 0; n < 4; ++n) {
      const int gcol = bn * 128 + wc * 64 + n * 16 + fr;
      const float bv = (EPI == 3) ? 0.f : bias[gcol];
      #pragma unroll
      for (int r = 0; r < 4; ++r) {
        const int grow = bm * 128 + wr * 64 + m * 16 + rq * 4 + r;
        const size_t off = (size_t)grow * N + gcol;
        float v = acc[m][n][r] + bv;
        if (EPI == 0) {
          ((unsigned short*)outp)[off] = f2bf(v);
        } else if (EPI == 1) {
          const float u2 = 1.5957691216f * v * (1.0f + 0.044715f * v * v);
          v = v / (1.0f + __expf(-u2));
          ((unsigned short*)outp)[off] = f2bf(v);
        } else {
          ((float*)outp)[off] = v + res[off];
        }
      }
    }
  }
}

// ---------------- LayerNorm (f32 in) -> bf16 out. 1 wave per row of 512.
__global__ __launch_bounds__(256)
void ln_bf16(const float* __restrict__ x, const float* __restrict__ w,
             const float* __restrict__ b, unsigned short* __restrict__ out)
{
  const int row  = blockIdx.x * 4 + (threadIdx.x >> 6);
  const int lane = threadIdx.x & 63;
  const float4* xr = (const float4*)(x + (size_t)row * C_);
  const float4 u = xr[lane * 2];
  const float4 v = xr[lane * 2 + 1];
  const float vals[8] = {u.x,u.y,u.z,u.w,v.x,v.y,v.z,v.w};
  float s = 0.f, s2 = 0.f;
  #pragma unroll
  for (int j = 0; j < 8; ++j) { s += vals[j]; s2 += vals[j]*vals[j]; }
  #pragma unroll
  for (int off = 1; off < 64; off <<= 1) {
    s  += __shfl_xor(s,  off);
    s2 += __shfl_xor(s2, off);
  }
  const float mean = s * (1.0f/512.0f);
  const float rstd = rsqrtf(s2 * (1.0f/512.0f) - mean*mean + 1e-5f);
  u16x8 o;
  #pragma unroll
  for (int j = 0; j < 8; ++j) {
    const int col = lane * 8 + j;
    o[j] = f2bf((vals[j] - mean) * rstd * w[col] + b[col]);
  }
  *(u16x8*)&out[(size_t)row * C_ + lane * 8] = o;
}

// ---------------- Window attention: block = (window, 4-head quarter).
// 256 threads = 4 waves; wave = one head; wave-private LDS slices, no barriers.
// Online softmax with fixed m=0 (bounded logits). Output DENSE in WINDOW
// order (49 consecutive 1KB rows/window -> full-line stores, no RMW
// amplification); proj un-permutes via winmap gather.
__global__ __launch_bounds__(256)
void attn_win3(const unsigned short* __restrict__ qkv,
               const unsigned short* __restrict__ biasBf,
               unsigned short* __restrict__ woutb, int i0)
{
  __shared__ float Ksh[4][NTOK*32];            // 25.1 KB
  __shared__ float Vsh[4][NTOK*32];            // 25.1 KB
  __shared__ unsigned short Bsh[4][NTOK*NTOK]; // 19.2 KB
  const int bi = blockIdx.x;
  const int qtr = bi & 3, winl = bi >> 2;
  const int bbl = winl >> 6, wy = (winl >> 3) & 7, wx = winl & 7;
  const int wave = threadIdx.x >> 6, lane = threadIdx.x & 63;
  const int head = qtr * 4 + wave;

  for (int i = lane; i < NTOK*NTOK; i += 64)
    Bsh[wave][i] = biasBf[head * (NTOK*NTOK) + i];

  float q[32];
  if (lane < NTOK) {
    const int r = lane / 7, c = lane % 7;
    const size_t gl = (size_t)bbl * 3136 + (size_t)((wy*7 + r) * 56 + (wx*7 + c));
    const unsigned short* qp = qkv + gl * 1536 + head * 32;
    #pragma unroll
    for (int d = 0; d < 32; d += 4) {
      const u16x4 qv = *(const u16x4*)&qp[d];
      const u16x4 kv = *(const u16x4*)&qp[512 + d];
      const u16x4 vv = *(const u16x4*)&qp[1024 + d];
      #pragma unroll
      for (int e = 0; e < 4; ++e) {
        q[d+e] = bf2f(qv[e]);
        Ksh[wave][lane*32 + d + e] = bf2f(kv[e]);
        Vsh[wave][lane*32 + d + e] = bf2f(vv[e]);
      }
    }
  }
  if (lane < NTOK) {
    float lsum = 0.f;
    float o[32];
    #pragma unroll
    for (int d = 0; d < 32; ++d) o[d] = 0.f;
    for (int j = 0; j < NTOK; ++j) {
      float dot = 0.f;
      #pragma unroll
      for (int d = 0; d < 32; ++d) dot += q[d] * Ksh[wave][j*32 + d];  // broadcast
      const float val = dot * 0.17677669529663687f
                      + bf2f(Bsh[wave][lane*NTOK + j]);
      const float e = __expf(val);
      lsum += e;
      #pragma unroll
      for (int d = 0; d < 32; ++d) o[d] += e * Vsh[wave][j*32 + d];    // broadcast
    }
    const float inv = 1.0f / lsum;
    unsigned short* op = woutb
        + ((size_t)((bbl + i0) * 64 + wy * 8 + wx) * 49 + lane) * 512 + head * 32;
    #pragma unroll
    for (int d = 0; d < 32; d += 4) {
      u16x4 ov;
      #pragma unroll
      for (int e = 0; e < 4; ++e) ov[e] = f2bf(o[d+e] * inv);
      *(u16x4*)&op[d] = ov;
    }
  }
}

// ---------------- small prep kernels
__global__ void build_bias(const float* __restrict__ table, const int* __restrict__ idx,
                           unsigned short* __restrict__ biasBf)
{
  const int i = blockIdx.x * 256 + threadIdx.x;
  if (i >= HEADS * NTOK * NTOK) return;
  const int h  = i / (NTOK*NTOK);
  const int ij = i - h * (NTOK*NTOK);
  biasBf[i] = f2bf(table[idx[ij] * HEADS + h]);
}

__global__ void conv_bf16(const float* __restrict__ in, unsigned short* __restrict__ out, int n4)
{
  const int i = blockIdx.x * 256 + threadIdx.x;
  if (i >= n4) return;
  const float4 v = ((const float4*)in)[i];
  u16x4 o; o[0]=f2bf(v.x); o[1]=f2bf(v.y); o[2]=f2bf(v.z); o[3]=f2bf(v.w);
  ((u16x4*)out)[i] = o;
}

extern "C" void kernel_launch(void* const* d_in, const int* in_sizes, int n_in,
                              void* d_out, int out_size, void* d_ws, size_t ws_size,
                              hipStream_t stream)
{
  const float* x     = (const float*)d_in[0];
  const float* n1w   = (const float*)d_in[1];
  const float* n1b   = (const float*)d_in[2];
  const float* qkvw  = (const float*)d_in[3];
  const float* qkvb  = (const float*)d_in[4];
  const float* projw = (const float*)d_in[5];
  const float* projb = (const float*)d_in[6];
  const float* rbt   = (const float*)d_in[7];
  const float* n2w   = (const float*)d_in[8];
  const float* n2b   = (const float*)d_in[9];
  const float* fc1w  = (const float*)d_in[10];
  const float* fc1b  = (const float*)d_in[11];
  const float* fc2w  = (const float*)d_in[12];
  const float* fc2b  = (const float*)d_in[13];
  const int*   rpi   = (const int*)d_in[14];
  float* out = (float*)d_out;

  // ---- adaptive workspace layout: fixed small region + bufX + reusable R ----
  char* p = (char*)d_ws;
  auto alloc = [&](size_t bytes) -> char* {
    char* q = p; p += (bytes + 255) & ~(size_t)255; return q;
  };
  unsigned short* wqB  = (unsigned short*)alloc((size_t)1536 * 512 * 2);
  unsigned short* wpB  = (unsigned short*)alloc((size_t)512  * 512 * 2);
  unsigned short* w1B  = (unsigned short*)alloc((size_t)2048 * 512 * 2);
  unsigned short* w2B  = (unsigned short*)alloc((size_t)512  * 2048 * 2);
  unsigned short* biasBf = (unsigned short*)alloc((size_t)HEADS * NTOK * NTOK * 2);
  unsigned short* bufX = (unsigned short*)alloc((size_t)ROWS * 512 * 2);
  const size_t used = (size_t)(p - (char*)d_ws);
  const size_t Rbytes = (ws_size > used) ? ws_size - used : 0;
  unsigned short* R = (unsigned short*)p;

  // qkv chunk: ic images; ic*3136 rows must be a multiple of 128 -> ic even
  int ic = 0;
  for (int c = 16; c >= 2; c >>= 1)
    if ((size_t)c * 3136 * 1536 * 2 <= Rbytes) { ic = c; break; }
  // mlp hidden chunk (N of FC1 = hc, multiple of 128)
  int hc = 0;
  for (int c = 2048; c >= 128; c >>= 1)
    if ((size_t)ROWS * c * 2 <= Rbytes) { hc = c; break; }
  if (ic == 0 || hc == 0) return;  // ws too small: clean failure, not a fault

  conv_bf16<<<(1536*512/4 + 255)/256, 256, 0, stream>>>(qkvw, wqB, 1536*512/4);
  conv_bf16<<<(512*512/4  + 255)/256, 256, 0, stream>>>(projw, wpB, 512*512/4);
  conv_bf16<<<(2048*512/4 + 255)/256, 256, 0, stream>>>(fc1w, w1B, 2048*512/4);
  conv_bf16<<<(512*2048/4 + 255)/256, 256, 0, stream>>>(fc2w, w2B, 512*2048/4);
  build_bias<<<(HEADS*NTOK*NTOK + 255)/256, 256, 0, stream>>>(rbt, rpi, biasBf);

  // LN1 -> bf16
  ln_bf16<<<ROWS/4, 256, 0, stream>>>(x, n1w, n1b, bufX);

  // QKV GEMM + window attention, chunked over images.
  for (int i0 = 0; i0 < B_; i0 += ic) {
    const int nbm = ic * 3136 / 128, nbn = 12;
    gemm_bt<0,0><<<nbm * nbn, 256, 0, stream>>>(
        bufX + (size_t)i0*3136*512, wqB, qkvb, nullptr, R, 1536, 512, 512, nbn);
    attn_win3<<<ic*64*4, 256, 0, stream>>>(R, biasBf, bufX, i0);
  }

  // proj GEMM (A gathered from window-order) + residual(x) -> d_out (f32)
  gemm_bt<2,1><<<(ROWS/128) * 4, 256, 0, stream>>>(
      bufX, wpB, projb, x, out, 512, 512, 512, 4);

  // LN2 -> bf16
  ln_bf16<<<ROWS/4, 256, 0, stream>>>(out, n2w, n2b, bufX);

  // MLP, chunked over hidden dim. FC2 accumulates into out (bias in chunk 0).
  for (int h0 = 0; h0 < 2048; h0 += hc) {
    gemm_bt<1,0><<<(ROWS/128) * (hc/128), 256, 0, stream>>>(
        bufX, w1B + (size_t)h0*512, fc1b + h0, nullptr, R, hc, 512, 512, hc/128);
    if (h0 == 0)
      gemm_bt<2,0><<<(ROWS/128) * 4, 256, 0, stream>>>(
          R, w2B + h0, fc2b, out, out, 512, hc, 2048, 4);
    else
      gemm_bt<3,0><<<(ROWS/128) * 4, 256, 0, stream>>>(
          R, w2B + h0, nullptr, out, out, 512, hc, 2048, 4);
  }
}